// Round 7
// baseline (608.352 us; speedup 1.0000x reference)
//
#include <hip/hip_runtime.h>
#include <hip/hip_bf16.h>

#define N_CELLS  200000
#define N_FACES  400000
#define N_POINTS 200000
#define E_CF     800000
#define E_FP     800000
#define E_PP     1200000
#define E_TOT    2800000   // E_CF+E_FP+E_PP
#define NROWS    800000    // N_FACES + N_POINTS + N_POINTS (concatenated)
#define FP_BASE  400000
#define PP_BASE  600000

typedef __attribute__((ext_vector_type(8))) short bf16x8;
typedef __attribute__((ext_vector_type(8))) unsigned short u16x8;
typedef __attribute__((ext_vector_type(4))) float f32x4;

__device__ __forceinline__ float bf2f(unsigned short u) {
    union { unsigned int i; float f; } v; v.i = ((unsigned int)u) << 16; return v.f;
}
__device__ __forceinline__ unsigned short f2bf(float f) {
    __hip_bfloat16 h = __float2bfloat16(f);
    return *reinterpret_cast<unsigned short*>(&h);
}

// ======== fused: zero counts + pack W_fp + pack [W_rt;W_pp] ========
__global__ __launch_bounds__(256) void k_pre(int* __restrict__ cnt,
                                             const float* __restrict__ W_fp,
                                             const float* __restrict__ W_rt,
                                             const float* __restrict__ W_pp,
                                             unsigned short* __restrict__ Bp_fp,
                                             unsigned short* __restrict__ Bp_fin) {
    int b = blockIdx.x;
    if (b < 3125) {
        int t = b * 256 + threadIdx.x;
        if (t < NROWS) cnt[t] = 0;
    } else if (b < 3173) {                        // pack W_fp: 48 blocks
        int t = (b - 3125) * 256 + threadIdx.x;   // 12288
        int j = t & 7, lane = (t >> 3) & 63, ct = (t >> 9) & 7, ks = t >> 12;
        int k = ks * 32 + ((lane >> 4) & 3) * 8 + j;
        int col = ct * 16 + (lane & 15);
        Bp_fp[t] = f2bf(W_fp[k * 128 + col]);
    } else {                                      // pack fin: 128 blocks
        int t = (b - 3173) * 256 + threadIdx.x;   // 32768
        int j = t & 7, lane = (t >> 3) & 63, ct = (t >> 9) & 7, ks = t >> 12;
        int k = ks * 32 + ((lane >> 4) & 3) * 8 + j;   // 0..255
        int col = ct * 16 + (lane & 15);
        float v = (k < 128) ? W_rt[k * 128 + col] : W_pp[(k - 128) * 128 + col];
        Bp_fin[t] = f2bf(v);
    }
}

// ======== fused histogram over all three graphs ========
__global__ __launch_bounds__(256) void k_hist3(const int* __restrict__ dst_cf,
                                               const int* __restrict__ dst_fp,
                                               const int* __restrict__ dst_pp,
                                               int* __restrict__ cnt) {
    int t = blockIdx.x * 256 + threadIdx.x;
    if (t >= E_TOT) return;
    int d;
    if (t < E_CF)             d = dst_cf[t];
    else if (t < E_CF + E_FP) d = FP_BASE + dst_fp[t - E_CF];
    else                      d = PP_BASE + dst_pp[t - E_CF - E_FP];
    atomicAdd(&cnt[d], 1);
}

// ======== scan over 800k counts (2048/block) ========
__global__ __launch_bounds__(256) void k_scan1(const int* __restrict__ cnt,
                                               int* __restrict__ bsum) {
    __shared__ int sh[256];
    int base = blockIdx.x * 2048 + threadIdx.x * 8;
    int s = 0;
#pragma unroll
    for (int i = 0; i < 8; ++i) { int idx = base + i; if (idx < NROWS) s += cnt[idx]; }
    sh[threadIdx.x] = s;
    __syncthreads();
    for (int off = 128; off > 0; off >>= 1) {
        if (threadIdx.x < off) sh[threadIdx.x] += sh[threadIdx.x + off];
        __syncthreads();
    }
    if (threadIdx.x == 0) bsum[blockIdx.x] = sh[0];
}

__global__ __launch_bounds__(512) void k_scan2(int* __restrict__ bsum, int nb) {
    __shared__ int sh[512];
    int t = threadIdx.x;
    int v = (t < nb) ? bsum[t] : 0;
    sh[t] = v;
    __syncthreads();
    for (int off = 1; off < 512; off <<= 1) {
        int add = (t >= off) ? sh[t - off] : 0;
        __syncthreads();
        sh[t] += add;
        __syncthreads();
    }
    if (t < nb) bsum[t] = sh[t] - v;
}

__global__ __launch_bounds__(256) void k_scan3(const int* __restrict__ cnt,
                                               const int* __restrict__ bsum,
                                               int* __restrict__ rowptr,
                                               int* __restrict__ cur) {
    __shared__ int sh[256];
    int base = blockIdx.x * 2048 + threadIdx.x * 8;
    int c[8]; int s = 0;
#pragma unroll
    for (int i = 0; i < 8; ++i) { int idx = base + i; c[i] = (idx < NROWS) ? cnt[idx] : 0; s += c[i]; }
    sh[threadIdx.x] = s;
    __syncthreads();
    int v = s;
    for (int off = 1; off < 256; off <<= 1) {
        int add = (threadIdx.x >= off) ? sh[threadIdx.x - off] : 0;
        __syncthreads();
        sh[threadIdx.x] += add;
        __syncthreads();
    }
    int excl = sh[threadIdx.x] - v + bsum[blockIdx.x];
#pragma unroll
    for (int i = 0; i < 8; ++i) {
        int idx = base + i;
        if (idx < NROWS) {
            rowptr[idx] = excl; cur[idx] = excl; excl += c[i];
            if (idx == NROWS - 1) rowptr[NROWS] = excl;
        }
    }
}

// ======== fused fill: permuted {src, ea_bits} records, nontemporal ========
__global__ __launch_bounds__(256) void k_fill3(const int* __restrict__ src_cf,
                                               const int* __restrict__ dst_cf,
                                               const float* __restrict__ ea_cf,
                                               const int* __restrict__ src_fp,
                                               const int* __restrict__ dst_fp,
                                               const float* __restrict__ ea_fp,
                                               const int* __restrict__ src_pp,
                                               const int* __restrict__ dst_pp,
                                               const float* __restrict__ ea_pp,
                                               int* __restrict__ cur,
                                               int2* __restrict__ pe) {
    int t = blockIdx.x * 256 + threadIdx.x;
    if (t >= E_TOT) return;
    int d, s; float w;
    if (t < E_CF) {
        d = dst_cf[t]; s = src_cf[t]; w = ea_cf[t];
    } else if (t < E_CF + E_FP) {
        int e = t - E_CF; d = FP_BASE + dst_fp[e]; s = src_fp[e]; w = ea_fp[e];
    } else {
        int e = t - E_CF - E_FP; d = PP_BASE + dst_pp[e]; s = src_pp[e]; w = ea_pp[e];
    }
    int slot = atomicAdd(&cur[d], 1);
    long long rec = (((long long)(unsigned)__float_as_int(w)) << 32) | (unsigned)s;
    __builtin_nontemporal_store(rec, (long long*)(pe + slot));
}

// ======== fused gather(cells->faces) + transform + concat ========
__global__ __launch_bounds__(256) void k_gather8_tf(const float* __restrict__ xc,
                                                    const int* __restrict__ ptr,
                                                    const int2* __restrict__ pe,
                                                    const float* __restrict__ x_face,
                                                    const float* __restrict__ W,
                                                    const float* __restrict__ b,
                                                    unsigned short* __restrict__ yfp) {
    __shared__ float Ws[512];
    __shared__ float bs[64];
    for (int i = threadIdx.x; i < 512; i += 256) Ws[i] = W[i];
    if (threadIdx.x < 64) bs[threadIdx.x] = b[threadIdx.x];
    __syncthreads();
    int r = blockIdx.x * 256 + threadIdx.x;
    if (r >= N_FACES) return;
    int e = ptr[r], end = ptr[r + 1];
    float a[8] = {};
    for (; e + 1 < end; e += 2) {
        int2 q0 = pe[e], q1 = pe[e + 1];
        float w0 = __int_as_float(q0.y), w1 = __int_as_float(q1.y);
        const float* p0 = xc + (size_t)q0.x * 8;
        const float* p1 = xc + (size_t)q1.x * 8;
        float4 u0 = *(const float4*)p0, u1 = *(const float4*)(p0 + 4);
        float4 v0 = *(const float4*)p1, v1 = *(const float4*)(p1 + 4);
        a[0] += w0 * u0.x + w1 * v0.x; a[1] += w0 * u0.y + w1 * v0.y;
        a[2] += w0 * u0.z + w1 * v0.z; a[3] += w0 * u0.w + w1 * v0.w;
        a[4] += w0 * u1.x + w1 * v1.x; a[5] += w0 * u1.y + w1 * v1.y;
        a[6] += w0 * u1.z + w1 * v1.z; a[7] += w0 * u1.w + w1 * v1.w;
    }
    if (e < end) {
        int2 q0 = pe[e];
        float w0 = __int_as_float(q0.y);
        const float* p0 = xc + (size_t)q0.x * 8;
        float4 u0 = *(const float4*)p0, u1 = *(const float4*)(p0 + 4);
        a[0] += w0 * u0.x; a[1] += w0 * u0.y; a[2] += w0 * u0.z; a[3] += w0 * u0.w;
        a[4] += w0 * u1.x; a[5] += w0 * u1.y; a[6] += w0 * u1.z; a[7] += w0 * u1.w;
    }
    // transform: y[j] = b[j] + sum_k a[k]*W[k][j], 4 chunks of 16 cols
    unsigned short* orow = yfp + (size_t)r * 96;
#pragma unroll
    for (int c4 = 0; c4 < 4; ++c4) {
        int j0 = c4 * 16;
        float acc[16];
#pragma unroll
        for (int i = 0; i < 16; ++i) acc[i] = bs[j0 + i];
#pragma unroll
        for (int k = 0; k < 8; ++k) {
            float x = a[k];
            const float* wr = Ws + k * 64 + j0;
#pragma unroll
            for (int i = 0; i < 16; ++i) acc[i] += x * wr[i];
        }
        u16x8 o0, o1;
#pragma unroll
        for (int i = 0; i < 8; ++i) { o0[i] = f2bf(acc[i]); o1[i] = f2bf(acc[8 + i]); }
        *(u16x8*)(orow + j0) = o0;
        *(u16x8*)(orow + j0 + 8) = o1;
    }
    float4 xf0 = *(const float4*)(x_face + (size_t)r * 8);
    float4 xf1 = *(const float4*)(x_face + (size_t)r * 8 + 4);
    u16x8 xo;
    xo[0] = f2bf(xf0.x); xo[1] = f2bf(xf0.y); xo[2] = f2bf(xf0.z); xo[3] = f2bf(xf0.w);
    xo[4] = f2bf(xf1.x); xo[5] = f2bf(xf1.y); xo[6] = f2bf(xf1.z); xo[7] = f2bf(xf1.w);
    *(u16x8*)(orow + 64) = xo;
}

// ======== faces->points gather (96 bf16 cols): 2 rows/wave ========
__global__ __launch_bounds__(256) void k_gather96(const unsigned short* __restrict__ feat,
                                                  const int* __restrict__ ptr,
                                                  const int2* __restrict__ pe,
                                                  unsigned short* __restrict__ aggf, int nRows) {
    int gw = (blockIdx.x * 256 + threadIdx.x) >> 6;
    int lane = threadIdx.x & 63;
    int row = gw * 2 + (lane >> 5);
    int l = lane & 31;
    if (row >= nRows) return;
    int e = ptr[row], end = ptr[row + 1];
    float a0 = 0.f, a1 = 0.f, a2 = 0.f;
    for (; e + 1 < end; e += 2) {
        int2 q0 = pe[e], q1 = pe[e + 1];
        float w0 = __int_as_float(q0.y), w1 = __int_as_float(q1.y);
        const unsigned short* f0 = feat + (size_t)q0.x * 96 + l;
        const unsigned short* f1 = feat + (size_t)q1.x * 96 + l;
        unsigned short x0 = f0[0], x1 = f0[32], x2 = f0[64];
        unsigned short y0 = f1[0], y1 = f1[32], y2 = f1[64];
        a0 += w0 * bf2f(x0) + w1 * bf2f(y0);
        a1 += w0 * bf2f(x1) + w1 * bf2f(y1);
        a2 += w0 * bf2f(x2) + w1 * bf2f(y2);
    }
    if (e < end) {
        int2 q0 = pe[e];
        float w0 = __int_as_float(q0.y);
        const unsigned short* f0 = feat + (size_t)q0.x * 96 + l;
        a0 += w0 * bf2f(f0[0]); a1 += w0 * bf2f(f0[32]); a2 += w0 * bf2f(f0[64]);
    }
    unsigned short* o = aggf + (size_t)row * 96 + l;
    o[0] = f2bf(a0); o[32] = f2bf(a1); o[64] = f2bf(a2);
}

// ======== points->points gather (128 bf16 cols): 2 rows/wave ========
__global__ __launch_bounds__(256) void k_gather128pp(const unsigned short* __restrict__ feat,
                                                     const int* __restrict__ ptr,
                                                     const int2* __restrict__ pe,
                                                     unsigned short* __restrict__ aggp, int nRows) {
    int gw = (blockIdx.x * 256 + threadIdx.x) >> 6;
    int lane = threadIdx.x & 63;
    int row = gw * 2 + (lane >> 5);
    int l = lane & 31;
    if (row >= nRows) return;
    int e = ptr[row], end = ptr[row + 1];
    float a0 = 0.f, a1 = 0.f, a2 = 0.f, a3 = 0.f;
    for (; e + 1 < end; e += 2) {
        int2 q0 = pe[e], q1 = pe[e + 1];
        float w0 = __int_as_float(q0.y), w1 = __int_as_float(q1.y);
        const unsigned short* f0 = feat + ((size_t)q0.x << 7) + l;
        const unsigned short* f1 = feat + ((size_t)q1.x << 7) + l;
        unsigned short x0 = f0[0], x1 = f0[32], x2 = f0[64], x3 = f0[96];
        unsigned short y0 = f1[0], y1 = f1[32], y2 = f1[64], y3 = f1[96];
        a0 += w0 * bf2f(x0) + w1 * bf2f(y0);
        a1 += w0 * bf2f(x1) + w1 * bf2f(y1);
        a2 += w0 * bf2f(x2) + w1 * bf2f(y2);
        a3 += w0 * bf2f(x3) + w1 * bf2f(y3);
    }
    if (e < end) {
        int2 q0 = pe[e];
        float w0 = __int_as_float(q0.y);
        const unsigned short* f0 = feat + ((size_t)q0.x << 7) + l;
        a0 += w0 * bf2f(f0[0]);  a1 += w0 * bf2f(f0[32]);
        a2 += w0 * bf2f(f0[64]); a3 += w0 * bf2f(f0[96]);
    }
    unsigned short* o = aggp + ((size_t)row << 7) + l;
    o[0] = f2bf(a0); o[32] = f2bf(a1); o[64] = f2bf(a2); o[96] = f2bf(a3);
}

// ======== MFMA: y_ptb = bf16(aggf[200k,96] @ W_fp + b_fp) ========
__global__ __launch_bounds__(256) void k_mfma96(const unsigned short* __restrict__ A,
                                                const unsigned short* __restrict__ Bp,
                                                const float* __restrict__ bias,
                                                unsigned short* __restrict__ O) {
    const int w = threadIdx.x >> 6;
    const int lane = threadIdx.x & 63;
    const int rg = w >> 1, cg = w & 1;
    const int row0 = blockIdx.x * 32 + rg * 16;
    bf16x8 bfr[3][4];
#pragma unroll
    for (int ks = 0; ks < 3; ++ks)
#pragma unroll
        for (int c = 0; c < 4; ++c) {
            int ct = cg * 4 + c;
            bfr[ks][c] = *(const bf16x8*)(Bp + ((size_t)(ks * 8 + ct) * 64 + lane) * 8);
        }
    f32x4 acc[4] = {};
    const unsigned short* arow = A + (size_t)(row0 + (lane & 15)) * 96 + ((lane >> 4) * 8);
#pragma unroll
    for (int ks = 0; ks < 3; ++ks) {
        bf16x8 af = *(const bf16x8*)(arow + ks * 32);
#pragma unroll
        for (int c = 0; c < 4; ++c)
            acc[c] = __builtin_amdgcn_mfma_f32_16x16x32_bf16(af, bfr[ks][c], acc[c], 0, 0, 0);
    }
    const int rbase = row0 + (lane >> 4) * 4;
#pragma unroll
    for (int c = 0; c < 4; ++c) {
        int gcol = cg * 64 + c * 16 + (lane & 15);
        float bv = bias[gcol];
#pragma unroll
        for (int r = 0; r < 4; ++r)
            O[(size_t)(rbase + r) * 128 + gcol] = f2bf(acc[c][r] + bv);
    }
}

// ======== MFMA: out = [y_ptb | aggp] @ [W_rt;W_pp] + b_pp ========
__global__ __launch_bounds__(256) void k_mfma_fin(const unsigned short* __restrict__ A1,
                                                  const unsigned short* __restrict__ A2,
                                                  const unsigned short* __restrict__ Bp,
                                                  const float* __restrict__ bias,
                                                  float* __restrict__ out) {
    const int w = threadIdx.x >> 6;
    const int lane = threadIdx.x & 63;
    const int rg = w >> 1, cg = w & 1;
    const int row0 = blockIdx.x * 32 + rg * 16;
    bf16x8 bfr[8][4];
#pragma unroll
    for (int ks = 0; ks < 8; ++ks)
#pragma unroll
        for (int c = 0; c < 4; ++c) {
            int ct = cg * 4 + c;
            bfr[ks][c] = *(const bf16x8*)(Bp + ((size_t)(ks * 8 + ct) * 64 + lane) * 8);
        }
    f32x4 acc[4] = {};
    const unsigned short* a1 = A1 + (size_t)(row0 + (lane & 15)) * 128 + ((lane >> 4) * 8);
    const unsigned short* a2 = A2 + (size_t)(row0 + (lane & 15)) * 128 + ((lane >> 4) * 8);
#pragma unroll
    for (int ks = 0; ks < 4; ++ks) {
        bf16x8 af = *(const bf16x8*)(a1 + ks * 32);
#pragma unroll
        for (int c = 0; c < 4; ++c)
            acc[c] = __builtin_amdgcn_mfma_f32_16x16x32_bf16(af, bfr[ks][c], acc[c], 0, 0, 0);
    }
#pragma unroll
    for (int ks = 0; ks < 4; ++ks) {
        bf16x8 af = *(const bf16x8*)(a2 + ks * 32);
#pragma unroll
        for (int c = 0; c < 4; ++c)
            acc[c] = __builtin_amdgcn_mfma_f32_16x16x32_bf16(af, bfr[ks + 4][c], acc[c], 0, 0, 0);
    }
    const int rbase = row0 + (lane >> 4) * 4;
#pragma unroll
    for (int c = 0; c < 4; ++c) {
        int gcol = cg * 64 + c * 16 + (lane & 15);
        float bv = bias[gcol];
#pragma unroll
        for (int r = 0; r < 4; ++r)
            out[(size_t)(rbase + r) * 128 + gcol] = acc[c][r] + bv;
    }
}

extern "C" void kernel_launch(void* const* d_in, const int* in_sizes, int n_in,
                              void* d_out, int out_size, void* d_ws, size_t ws_size,
                              hipStream_t stream) {
    const float* x_centers = (const float*)d_in[0];
    const float* x_face    = (const float*)d_in[1];
    const float* W_cf      = (const float*)d_in[2];
    const float* b_cf      = (const float*)d_in[3];
    const float* W_fp      = (const float*)d_in[4];
    const float* b_fp      = (const float*)d_in[5];
    const float* W_pp      = (const float*)d_in[6];
    const float* W_rt      = (const float*)d_in[7];
    const float* b_pp      = (const float*)d_in[8];
    const float* ea_cf     = (const float*)d_in[9];
    const float* ea_fp     = (const float*)d_in[10];
    const float* ea_pp     = (const float*)d_in[11];
    const int* src_cf      = (const int*)d_in[12];
    const int* dst_cf      = (const int*)d_in[13];
    const int* src_fp      = (const int*)d_in[14];
    const int* dst_fp      = (const int*)d_in[15];
    const int* src_pp      = (const int*)d_in[16];
    const int* dst_pp      = (const int*)d_in[17];
    float* out = (float*)d_out;

    char* ws = (char*)d_ws;
    unsigned short* yfp    = (unsigned short*)(ws + 0);           // bf16 [400k][96]  76.8MB
    unsigned short* aggf   = (unsigned short*)(ws + 80000000);    // bf16 [200k][96]  38.4MB
    unsigned short* y_ptb  = (unsigned short*)(ws + 120000000);   // bf16 [200k][128] 51.2MB
    unsigned short* aggp   = (unsigned short*)(ws + 172000000);   // bf16 [200k][128] 51.2MB
    int2* pe_all           = (int2*)(ws + 224000000);             // 2.8M recs 22.4MB
    int*  cnt_all          = (int*)(ws + 247000000);              // 800000 (counts -> cursors)
    int*  ptr_all          = (int*)(ws + 251000000);              // 800001 rowptr
    int*  bsum             = (int*)(ws + 255000000);              // 391
    unsigned short* Bp_fp  = (unsigned short*)(ws + 255100000);   // 24KB
    unsigned short* Bp_fin = (unsigned short*)(ws + 255200000);   // 64KB

    // CSR build (fused across all three graphs)
    k_pre<<<3301, 256, 0, stream>>>(cnt_all, W_fp, W_rt, W_pp, Bp_fp, Bp_fin);
    k_hist3<<<10938, 256, 0, stream>>>(dst_cf, dst_fp, dst_pp, cnt_all);
    k_scan1<<<391, 256, 0, stream>>>(cnt_all, bsum);
    k_scan2<<<1, 512, 0, stream>>>(bsum, 391);
    k_scan3<<<391, 256, 0, stream>>>(cnt_all, bsum, ptr_all, cnt_all);
    k_fill3<<<10938, 256, 0, stream>>>(src_cf, dst_cf, ea_cf, src_fp, dst_fp, ea_fp,
                                       src_pp, dst_pp, ea_pp, cnt_all, pe_all);
    // pipeline
    k_gather8_tf<<<1563, 256, 0, stream>>>(x_centers, ptr_all, pe_all, x_face, W_cf, b_cf, yfp);
    k_gather96<<<25000, 256, 0, stream>>>(yfp, ptr_all + FP_BASE, pe_all, aggf, N_POINTS);
    k_mfma96<<<6250, 256, 0, stream>>>(aggf, Bp_fp, b_fp, y_ptb);
    k_gather128pp<<<25000, 256, 0, stream>>>(y_ptb, ptr_all + PP_BASE, pe_all, aggp, N_POINTS);
    k_mfma_fin<<<6250, 256, 0, stream>>>(y_ptb, aggp, Bp_fin, b_pp, out);
}

// Round 8
// 563.812 us; speedup vs baseline: 1.0790x; 1.0790x over previous
//
#include <hip/hip_runtime.h>
#include <hip/hip_bf16.h>

#define N_CELLS  200000
#define N_FACES  400000
#define N_POINTS 200000
#define E_CF     800000
#define E_FP     800000
#define E_PP     1200000
#define E_TOT    2800000
#define NROWS    800000    // N_FACES + N_POINTS + N_POINTS (concatenated)
#define FP_BASE  400000
#define PP_BASE  600000

typedef __attribute__((ext_vector_type(8))) short bf16x8;
typedef __attribute__((ext_vector_type(8))) unsigned short u16x8;
typedef __attribute__((ext_vector_type(4))) float f32x4;

__device__ __forceinline__ float bf2f(unsigned short u) {
    union { unsigned int i; float f; } v; v.i = ((unsigned int)u) << 16; return v.f;
}
__device__ __forceinline__ unsigned short f2bf(float f) {
    __hip_bfloat16 h = __float2bfloat16(f);
    return *reinterpret_cast<unsigned short*>(&h);
}

// ======== fused: zero counts + pack W_fp + pack [W_rt;W_pp] ========
__global__ __launch_bounds__(256) void k_pre(int* __restrict__ cnt,
                                             const float* __restrict__ W_fp,
                                             const float* __restrict__ W_rt,
                                             const float* __restrict__ W_pp,
                                             unsigned short* __restrict__ Bp_fp,
                                             unsigned short* __restrict__ Bp_fin) {
    int b = blockIdx.x;
    if (b < 3125) {
        int t = b * 256 + threadIdx.x;
        if (t < NROWS) cnt[t] = 0;
    } else if (b < 3173) {                        // pack W_fp: 48 blocks
        int t = (b - 3125) * 256 + threadIdx.x;   // 12288
        int j = t & 7, lane = (t >> 3) & 63, ct = (t >> 9) & 7, ks = t >> 12;
        int k = ks * 32 + ((lane >> 4) & 3) * 8 + j;
        int col = ct * 16 + (lane & 15);
        Bp_fp[t] = f2bf(W_fp[k * 128 + col]);
    } else {                                      // pack fin: 128 blocks
        int t = (b - 3173) * 256 + threadIdx.x;   // 32768
        int j = t & 7, lane = (t >> 3) & 63, ct = (t >> 9) & 7, ks = t >> 12;
        int k = ks * 32 + ((lane >> 4) & 3) * 8 + j;   // 0..255
        int col = ct * 16 + (lane & 15);
        float v = (k < 128) ? W_rt[k * 128 + col] : W_pp[(k - 128) * 128 + col];
        Bp_fin[t] = f2bf(v);
    }
}

// ======== fused histogram over all three graphs ========
__global__ __launch_bounds__(256) void k_hist3(const int* __restrict__ dst_cf,
                                               const int* __restrict__ dst_fp,
                                               const int* __restrict__ dst_pp,
                                               int* __restrict__ cnt) {
    int t = blockIdx.x * 256 + threadIdx.x;
    if (t >= E_TOT) return;
    int d;
    if (t < E_CF)             d = dst_cf[t];
    else if (t < E_CF + E_FP) d = FP_BASE + dst_fp[t - E_CF];
    else                      d = PP_BASE + dst_pp[t - E_CF - E_FP];
    atomicAdd(&cnt[d], 1);
}

// ======== scan over 800k counts (2048/block) ========
__global__ __launch_bounds__(256) void k_scan1(const int* __restrict__ cnt,
                                               int* __restrict__ bsum) {
    __shared__ int sh[256];
    int base = blockIdx.x * 2048 + threadIdx.x * 8;
    int s = 0;
#pragma unroll
    for (int i = 0; i < 8; ++i) { int idx = base + i; if (idx < NROWS) s += cnt[idx]; }
    sh[threadIdx.x] = s;
    __syncthreads();
    for (int off = 128; off > 0; off >>= 1) {
        if (threadIdx.x < off) sh[threadIdx.x] += sh[threadIdx.x + off];
        __syncthreads();
    }
    if (threadIdx.x == 0) bsum[blockIdx.x] = sh[0];
}

__global__ __launch_bounds__(512) void k_scan2(int* __restrict__ bsum, int nb) {
    __shared__ int sh[512];
    int t = threadIdx.x;
    int v = (t < nb) ? bsum[t] : 0;
    sh[t] = v;
    __syncthreads();
    for (int off = 1; off < 512; off <<= 1) {
        int add = (t >= off) ? sh[t - off] : 0;
        __syncthreads();
        sh[t] += add;
        __syncthreads();
    }
    if (t < nb) bsum[t] = sh[t] - v;
}

__global__ __launch_bounds__(256) void k_scan3(const int* __restrict__ cnt,
                                               const int* __restrict__ bsum,
                                               int* __restrict__ rowptr,
                                               int* __restrict__ cur) {
    __shared__ int sh[256];
    int base = blockIdx.x * 2048 + threadIdx.x * 8;
    int c[8]; int s = 0;
#pragma unroll
    for (int i = 0; i < 8; ++i) { int idx = base + i; c[i] = (idx < NROWS) ? cnt[idx] : 0; s += c[i]; }
    sh[threadIdx.x] = s;
    __syncthreads();
    int v = s;
    for (int off = 1; off < 256; off <<= 1) {
        int add = (threadIdx.x >= off) ? sh[threadIdx.x - off] : 0;
        __syncthreads();
        sh[threadIdx.x] += add;
        __syncthreads();
    }
    int excl = sh[threadIdx.x] - v + bsum[blockIdx.x];
#pragma unroll
    for (int i = 0; i < 8; ++i) {
        int idx = base + i;
        if (idx < NROWS) {
            rowptr[idx] = excl; cur[idx] = excl; excl += c[i];
            if (idx == NROWS - 1) rowptr[NROWS] = excl;
        }
    }
}

// ======== fill for cf graph only ========
__global__ __launch_bounds__(256) void k_fill_cf(const int* __restrict__ src_cf,
                                                 const int* __restrict__ dst_cf,
                                                 const float* __restrict__ ea_cf,
                                                 int* __restrict__ cur,
                                                 int2* __restrict__ pe) {
    int t = blockIdx.x * 256 + threadIdx.x;
    if (t >= E_CF) return;
    int d = dst_cf[t];
    int slot = atomicAdd(&cur[d], 1);
    int2 r; r.x = src_cf[t]; r.y = __float_as_int(ea_cf[t]);
    pe[slot] = r;
}

// ======== MEGA: fill_fp ∥ fill_pp ∥ gather8_tf (independent tasks, one launch) ========
#define MEGA_FP   3125                 // fill_fp blocks
#define MEGA_PP   4688                 // fill_pp blocks
#define MEGA_G8   1563                 // gather8_tf blocks
__global__ __launch_bounds__(256) void k_mega(const int* __restrict__ src_fp,
                                              const int* __restrict__ dst_fp,
                                              const float* __restrict__ ea_fp,
                                              const int* __restrict__ src_pp,
                                              const int* __restrict__ dst_pp,
                                              const float* __restrict__ ea_pp,
                                              int* __restrict__ cur,
                                              int2* __restrict__ pe,
                                              const float* __restrict__ xc,
                                              const int* __restrict__ ptr,
                                              const float* __restrict__ x_face,
                                              const float* __restrict__ W,
                                              const float* __restrict__ bvec,
                                              unsigned short* __restrict__ yfp) {
    __shared__ float Ws[512];
    __shared__ float bs[64];
    int b = blockIdx.x;
    if (b < MEGA_FP) {                            // ---- fill fp ----
        int t = b * 256 + threadIdx.x;
        if (t < E_FP) {
            int d = FP_BASE + dst_fp[t];
            int slot = atomicAdd(&cur[d], 1);
            int2 r; r.x = src_fp[t]; r.y = __float_as_int(ea_fp[t]);
            pe[slot] = r;
        }
        return;
    }
    if (b < MEGA_FP + MEGA_PP) {                  // ---- fill pp ----
        int t = (b - MEGA_FP) * 256 + threadIdx.x;
        if (t < E_PP) {
            int d = PP_BASE + dst_pp[t];
            int slot = atomicAdd(&cur[d], 1);
            int2 r; r.x = src_pp[t]; r.y = __float_as_int(ea_pp[t]);
            pe[slot] = r;
        }
        return;
    }
    // ---- gather8_tf ----
    for (int i = threadIdx.x; i < 512; i += 256) Ws[i] = W[i];
    if (threadIdx.x < 64) bs[threadIdx.x] = bvec[threadIdx.x];
    __syncthreads();
    int r = (b - MEGA_FP - MEGA_PP) * 256 + threadIdx.x;
    if (r >= N_FACES) return;
    int e = ptr[r], end = ptr[r + 1];
    float a[8] = {};
    for (; e + 1 < end; e += 2) {
        int2 q0 = pe[e], q1 = pe[e + 1];
        float w0 = __int_as_float(q0.y), w1 = __int_as_float(q1.y);
        const float* p0 = xc + (size_t)q0.x * 8;
        const float* p1 = xc + (size_t)q1.x * 8;
        float4 u0 = *(const float4*)p0, u1 = *(const float4*)(p0 + 4);
        float4 v0 = *(const float4*)p1, v1 = *(const float4*)(p1 + 4);
        a[0] += w0 * u0.x + w1 * v0.x; a[1] += w0 * u0.y + w1 * v0.y;
        a[2] += w0 * u0.z + w1 * v0.z; a[3] += w0 * u0.w + w1 * v0.w;
        a[4] += w0 * u1.x + w1 * v1.x; a[5] += w0 * u1.y + w1 * v1.y;
        a[6] += w0 * u1.z + w1 * v1.z; a[7] += w0 * u1.w + w1 * v1.w;
    }
    if (e < end) {
        int2 q0 = pe[e];
        float w0 = __int_as_float(q0.y);
        const float* p0 = xc + (size_t)q0.x * 8;
        float4 u0 = *(const float4*)p0, u1 = *(const float4*)(p0 + 4);
        a[0] += w0 * u0.x; a[1] += w0 * u0.y; a[2] += w0 * u0.z; a[3] += w0 * u0.w;
        a[4] += w0 * u1.x; a[5] += w0 * u1.y; a[6] += w0 * u1.z; a[7] += w0 * u1.w;
    }
    unsigned short* orow = yfp + (size_t)r * 96;
#pragma unroll
    for (int c4 = 0; c4 < 4; ++c4) {
        int j0 = c4 * 16;
        float acc[16];
#pragma unroll
        for (int i = 0; i < 16; ++i) acc[i] = bs[j0 + i];
#pragma unroll
        for (int k = 0; k < 8; ++k) {
            float x = a[k];
            const float* wr = Ws + k * 64 + j0;
#pragma unroll
            for (int i = 0; i < 16; ++i) acc[i] += x * wr[i];
        }
        u16x8 o0, o1;
#pragma unroll
        for (int i = 0; i < 8; ++i) { o0[i] = f2bf(acc[i]); o1[i] = f2bf(acc[8 + i]); }
        *(u16x8*)(orow + j0) = o0;
        *(u16x8*)(orow + j0 + 8) = o1;
    }
    float4 xf0 = *(const float4*)(x_face + (size_t)r * 8);
    float4 xf1 = *(const float4*)(x_face + (size_t)r * 8 + 4);
    u16x8 xo;
    xo[0] = f2bf(xf0.x); xo[1] = f2bf(xf0.y); xo[2] = f2bf(xf0.z); xo[3] = f2bf(xf0.w);
    xo[4] = f2bf(xf1.x); xo[5] = f2bf(xf1.y); xo[6] = f2bf(xf1.z); xo[7] = f2bf(xf1.w);
    *(u16x8*)(orow + 64) = xo;
}

// ======== faces->points gather (96 bf16 cols): 2 rows/wave ========
__global__ __launch_bounds__(256) void k_gather96(const unsigned short* __restrict__ feat,
                                                  const int* __restrict__ ptr,
                                                  const int2* __restrict__ pe,
                                                  unsigned short* __restrict__ aggf, int nRows) {
    int gw = (blockIdx.x * 256 + threadIdx.x) >> 6;
    int lane = threadIdx.x & 63;
    int row = gw * 2 + (lane >> 5);
    int l = lane & 31;
    if (row >= nRows) return;
    int e = ptr[row], end = ptr[row + 1];
    float a0 = 0.f, a1 = 0.f, a2 = 0.f;
    for (; e + 1 < end; e += 2) {
        int2 q0 = pe[e], q1 = pe[e + 1];
        float w0 = __int_as_float(q0.y), w1 = __int_as_float(q1.y);
        const unsigned short* f0 = feat + (size_t)q0.x * 96 + l;
        const unsigned short* f1 = feat + (size_t)q1.x * 96 + l;
        unsigned short x0 = f0[0], x1 = f0[32], x2 = f0[64];
        unsigned short y0 = f1[0], y1 = f1[32], y2 = f1[64];
        a0 += w0 * bf2f(x0) + w1 * bf2f(y0);
        a1 += w0 * bf2f(x1) + w1 * bf2f(y1);
        a2 += w0 * bf2f(x2) + w1 * bf2f(y2);
    }
    if (e < end) {
        int2 q0 = pe[e];
        float w0 = __int_as_float(q0.y);
        const unsigned short* f0 = feat + (size_t)q0.x * 96 + l;
        a0 += w0 * bf2f(f0[0]); a1 += w0 * bf2f(f0[32]); a2 += w0 * bf2f(f0[64]);
    }
    unsigned short* o = aggf + (size_t)row * 96 + l;
    o[0] = f2bf(a0); o[32] = f2bf(a1); o[64] = f2bf(a2);
}

// ======== points->points gather (128 bf16 cols): 2 rows/wave ========
__global__ __launch_bounds__(256) void k_gather128pp(const unsigned short* __restrict__ feat,
                                                     const int* __restrict__ ptr,
                                                     const int2* __restrict__ pe,
                                                     unsigned short* __restrict__ aggp, int nRows) {
    int gw = (blockIdx.x * 256 + threadIdx.x) >> 6;
    int lane = threadIdx.x & 63;
    int row = gw * 2 + (lane >> 5);
    int l = lane & 31;
    if (row >= nRows) return;
    int e = ptr[row], end = ptr[row + 1];
    float a0 = 0.f, a1 = 0.f, a2 = 0.f, a3 = 0.f;
    for (; e + 1 < end; e += 2) {
        int2 q0 = pe[e], q1 = pe[e + 1];
        float w0 = __int_as_float(q0.y), w1 = __int_as_float(q1.y);
        const unsigned short* f0 = feat + ((size_t)q0.x << 7) + l;
        const unsigned short* f1 = feat + ((size_t)q1.x << 7) + l;
        unsigned short x0 = f0[0], x1 = f0[32], x2 = f0[64], x3 = f0[96];
        unsigned short y0 = f1[0], y1 = f1[32], y2 = f1[64], y3 = f1[96];
        a0 += w0 * bf2f(x0) + w1 * bf2f(y0);
        a1 += w0 * bf2f(x1) + w1 * bf2f(y1);
        a2 += w0 * bf2f(x2) + w1 * bf2f(y2);
        a3 += w0 * bf2f(x3) + w1 * bf2f(y3);
    }
    if (e < end) {
        int2 q0 = pe[e];
        float w0 = __int_as_float(q0.y);
        const unsigned short* f0 = feat + ((size_t)q0.x << 7) + l;
        a0 += w0 * bf2f(f0[0]);  a1 += w0 * bf2f(f0[32]);
        a2 += w0 * bf2f(f0[64]); a3 += w0 * bf2f(f0[96]);
    }
    unsigned short* o = aggp + ((size_t)row << 7) + l;
    o[0] = f2bf(a0); o[32] = f2bf(a1); o[64] = f2bf(a2); o[96] = f2bf(a3);
}

// ======== MFMA: y_ptb = bf16(aggf[200k,96] @ W_fp + b_fp) ========
__global__ __launch_bounds__(256) void k_mfma96(const unsigned short* __restrict__ A,
                                                const unsigned short* __restrict__ Bp,
                                                const float* __restrict__ bias,
                                                unsigned short* __restrict__ O) {
    const int w = threadIdx.x >> 6;
    const int lane = threadIdx.x & 63;
    const int rg = w >> 1, cg = w & 1;
    const int row0 = blockIdx.x * 32 + rg * 16;
    bf16x8 bfr[3][4];
#pragma unroll
    for (int ks = 0; ks < 3; ++ks)
#pragma unroll
        for (int c = 0; c < 4; ++c) {
            int ct = cg * 4 + c;
            bfr[ks][c] = *(const bf16x8*)(Bp + ((size_t)(ks * 8 + ct) * 64 + lane) * 8);
        }
    f32x4 acc[4] = {};
    const unsigned short* arow = A + (size_t)(row0 + (lane & 15)) * 96 + ((lane >> 4) * 8);
#pragma unroll
    for (int ks = 0; ks < 3; ++ks) {
        bf16x8 af = *(const bf16x8*)(arow + ks * 32);
#pragma unroll
        for (int c = 0; c < 4; ++c)
            acc[c] = __builtin_amdgcn_mfma_f32_16x16x32_bf16(af, bfr[ks][c], acc[c], 0, 0, 0);
    }
    const int rbase = row0 + (lane >> 4) * 4;
#pragma unroll
    for (int c = 0; c < 4; ++c) {
        int gcol = cg * 64 + c * 16 + (lane & 15);
        float bv = bias[gcol];
#pragma unroll
        for (int r = 0; r < 4; ++r)
            O[(size_t)(rbase + r) * 128 + gcol] = f2bf(acc[c][r] + bv);
    }
}

// ======== MFMA: out = [y_ptb | aggp] @ [W_rt;W_pp] + b_pp ========
__global__ __launch_bounds__(256) void k_mfma_fin(const unsigned short* __restrict__ A1,
                                                  const unsigned short* __restrict__ A2,
                                                  const unsigned short* __restrict__ Bp,
                                                  const float* __restrict__ bias,
                                                  float* __restrict__ out) {
    const int w = threadIdx.x >> 6;
    const int lane = threadIdx.x & 63;
    const int rg = w >> 1, cg = w & 1;
    const int row0 = blockIdx.x * 32 + rg * 16;
    bf16x8 bfr[8][4];
#pragma unroll
    for (int ks = 0; ks < 8; ++ks)
#pragma unroll
        for (int c = 0; c < 4; ++c) {
            int ct = cg * 4 + c;
            bfr[ks][c] = *(const bf16x8*)(Bp + ((size_t)(ks * 8 + ct) * 64 + lane) * 8);
        }
    f32x4 acc[4] = {};
    const unsigned short* a1 = A1 + (size_t)(row0 + (lane & 15)) * 128 + ((lane >> 4) * 8);
    const unsigned short* a2 = A2 + (size_t)(row0 + (lane & 15)) * 128 + ((lane >> 4) * 8);
#pragma unroll
    for (int ks = 0; ks < 4; ++ks) {
        bf16x8 af = *(const bf16x8*)(a1 + ks * 32);
#pragma unroll
        for (int c = 0; c < 4; ++c)
            acc[c] = __builtin_amdgcn_mfma_f32_16x16x32_bf16(af, bfr[ks][c], acc[c], 0, 0, 0);
    }
#pragma unroll
    for (int ks = 0; ks < 4; ++ks) {
        bf16x8 af = *(const bf16x8*)(a2 + ks * 32);
#pragma unroll
        for (int c = 0; c < 4; ++c)
            acc[c] = __builtin_amdgcn_mfma_f32_16x16x32_bf16(af, bfr[ks + 4][c], acc[c], 0, 0, 0);
    }
    const int rbase = row0 + (lane >> 4) * 4;
#pragma unroll
    for (int c = 0; c < 4; ++c) {
        int gcol = cg * 64 + c * 16 + (lane & 15);
        float bv = bias[gcol];
#pragma unroll
        for (int r = 0; r < 4; ++r)
            out[(size_t)(rbase + r) * 128 + gcol] = acc[c][r] + bv;
    }
}

extern "C" void kernel_launch(void* const* d_in, const int* in_sizes, int n_in,
                              void* d_out, int out_size, void* d_ws, size_t ws_size,
                              hipStream_t stream) {
    const float* x_centers = (const float*)d_in[0];
    const float* x_face    = (const float*)d_in[1];
    const float* W_cf      = (const float*)d_in[2];
    const float* b_cf      = (const float*)d_in[3];
    const float* W_fp      = (const float*)d_in[4];
    const float* b_fp      = (const float*)d_in[5];
    const float* W_pp      = (const float*)d_in[6];
    const float* W_rt      = (const float*)d_in[7];
    const float* b_pp      = (const float*)d_in[8];
    const float* ea_cf     = (const float*)d_in[9];
    const float* ea_fp     = (const float*)d_in[10];
    const float* ea_pp     = (const float*)d_in[11];
    const int* src_cf      = (const int*)d_in[12];
    const int* dst_cf      = (const int*)d_in[13];
    const int* src_fp      = (const int*)d_in[14];
    const int* dst_fp      = (const int*)d_in[15];
    const int* src_pp      = (const int*)d_in[16];
    const int* dst_pp      = (const int*)d_in[17];
    float* out = (float*)d_out;

    char* ws = (char*)d_ws;
    unsigned short* yfp    = (unsigned short*)(ws + 0);           // bf16 [400k][96]  76.8MB
    unsigned short* aggf   = (unsigned short*)(ws + 80000000);    // bf16 [200k][96]  38.4MB
    unsigned short* y_ptb  = (unsigned short*)(ws + 120000000);   // bf16 [200k][128] 51.2MB
    unsigned short* aggp   = (unsigned short*)(ws + 172000000);   // bf16 [200k][128] 51.2MB
    int2* pe_all           = (int2*)(ws + 224000000);             // 2.8M recs 22.4MB
    int*  cnt_all          = (int*)(ws + 247000000);              // 800000 (counts -> cursors)
    int*  ptr_all          = (int*)(ws + 251000000);              // 800001 rowptr
    int*  bsum             = (int*)(ws + 255000000);              // 391
    unsigned short* Bp_fp  = (unsigned short*)(ws + 255100000);   // 24KB
    unsigned short* Bp_fin = (unsigned short*)(ws + 255200000);   // 64KB

    // CSR build
    k_pre<<<3301, 256, 0, stream>>>(cnt_all, W_fp, W_rt, W_pp, Bp_fp, Bp_fin);
    k_hist3<<<10938, 256, 0, stream>>>(dst_cf, dst_fp, dst_pp, cnt_all);
    k_scan1<<<391, 256, 0, stream>>>(cnt_all, bsum);
    k_scan2<<<1, 512, 0, stream>>>(bsum, 391);
    k_scan3<<<391, 256, 0, stream>>>(cnt_all, bsum, ptr_all, cnt_all);
    k_fill_cf<<<3125, 256, 0, stream>>>(src_cf, dst_cf, ea_cf, cnt_all, pe_all);
    // MEGA: fill_fp ∥ fill_pp ∥ gather8_tf (gather needs only cf records)
    k_mega<<<MEGA_FP + MEGA_PP + MEGA_G8, 256, 0, stream>>>(
        src_fp, dst_fp, ea_fp, src_pp, dst_pp, ea_pp, cnt_all, pe_all,
        x_centers, ptr_all, x_face, W_cf, b_cf, yfp);
    // remaining pipeline
    k_gather96<<<25000, 256, 0, stream>>>(yfp, ptr_all + FP_BASE, pe_all, aggf, N_POINTS);
    k_mfma96<<<6250, 256, 0, stream>>>(aggf, Bp_fp, b_fp, y_ptb);
    k_gather128pp<<<25000, 256, 0, stream>>>(y_ptb, ptr_all + PP_BASE, pe_all, aggp, N_POINTS);
    k_mfma_fin<<<6250, 256, 0, stream>>>(y_ptb, aggp, Bp_fin, b_pp, out);
}

// Round 9
// 511.700 us; speedup vs baseline: 1.1889x; 1.1018x over previous
//
#include <hip/hip_runtime.h>
#include <hip/hip_bf16.h>

#define N_CELLS  200000
#define N_FACES  400000
#define N_POINTS 200000
#define E_CF     800000
#define E_FP     800000
#define E_PP     1200000
#define E_TOT    2800000
#define NROWS    800000    // N_FACES + N_POINTS + N_POINTS (concatenated)
#define FP_BASE  400000
#define PP_BASE  600000
#define FILL_BLOCKS 2048   // multiple of 8; 256 blocks per partition

typedef __attribute__((ext_vector_type(8))) short bf16x8;
typedef __attribute__((ext_vector_type(8))) unsigned short u16x8;
typedef __attribute__((ext_vector_type(4))) float f32x4;

// equal-expected-record row partition boundaries (density 2/4/6 per row)
__constant__ int part_bounds[9] = {0, 175000, 350000, 462500, 550000,
                                   625000, 683334, 741667, 800000};

__device__ __forceinline__ float bf2f(unsigned short u) {
    union { unsigned int i; float f; } v; v.i = ((unsigned int)u) << 16; return v.f;
}
__device__ __forceinline__ unsigned short f2bf(float f) {
    __hip_bfloat16 h = __float2bfloat16(f);
    return *reinterpret_cast<unsigned short*>(&h);
}

// ======== fused: zero counts + pack W_fp + pack [W_rt;W_pp] ========
__global__ __launch_bounds__(256) void k_pre(int* __restrict__ cnt,
                                             const float* __restrict__ W_fp,
                                             const float* __restrict__ W_rt,
                                             const float* __restrict__ W_pp,
                                             unsigned short* __restrict__ Bp_fp,
                                             unsigned short* __restrict__ Bp_fin) {
    int b = blockIdx.x;
    if (b < 3125) {
        int t = b * 256 + threadIdx.x;
        if (t < NROWS) cnt[t] = 0;
    } else if (b < 3173) {                        // pack W_fp: 48 blocks
        int t = (b - 3125) * 256 + threadIdx.x;   // 12288
        int j = t & 7, lane = (t >> 3) & 63, ct = (t >> 9) & 7, ks = t >> 12;
        int k = ks * 32 + ((lane >> 4) & 3) * 8 + j;
        int col = ct * 16 + (lane & 15);
        Bp_fp[t] = f2bf(W_fp[k * 128 + col]);
    } else {                                      // pack fin: 128 blocks
        int t = (b - 3173) * 256 + threadIdx.x;   // 32768
        int j = t & 7, lane = (t >> 3) & 63, ct = (t >> 9) & 7, ks = t >> 12;
        int k = ks * 32 + ((lane >> 4) & 3) * 8 + j;   // 0..255
        int col = ct * 16 + (lane & 15);
        float v = (k < 128) ? W_rt[k * 128 + col] : W_pp[(k - 128) * 128 + col];
        Bp_fin[t] = f2bf(v);
    }
}

// ======== fused histogram over all three graphs ========
__global__ __launch_bounds__(256) void k_hist3(const int* __restrict__ dst_cf,
                                               const int* __restrict__ dst_fp,
                                               const int* __restrict__ dst_pp,
                                               int* __restrict__ cnt) {
    int t = blockIdx.x * 256 + threadIdx.x;
    if (t >= E_TOT) return;
    int d;
    if (t < E_CF)             d = dst_cf[t];
    else if (t < E_CF + E_FP) d = FP_BASE + dst_fp[t - E_CF];
    else                      d = PP_BASE + dst_pp[t - E_CF - E_FP];
    atomicAdd(&cnt[d], 1);
}

// ======== scan over 800k counts (2048/block) ========
__global__ __launch_bounds__(256) void k_scan1(const int* __restrict__ cnt,
                                               int* __restrict__ bsum) {
    __shared__ int sh[256];
    int base = blockIdx.x * 2048 + threadIdx.x * 8;
    int s = 0;
#pragma unroll
    for (int i = 0; i < 8; ++i) { int idx = base + i; if (idx < NROWS) s += cnt[idx]; }
    sh[threadIdx.x] = s;
    __syncthreads();
    for (int off = 128; off > 0; off >>= 1) {
        if (threadIdx.x < off) sh[threadIdx.x] += sh[threadIdx.x + off];
        __syncthreads();
    }
    if (threadIdx.x == 0) bsum[blockIdx.x] = sh[0];
}

__global__ __launch_bounds__(512) void k_scan2(int* __restrict__ bsum, int nb) {
    __shared__ int sh[512];
    int t = threadIdx.x;
    int v = (t < nb) ? bsum[t] : 0;
    sh[t] = v;
    __syncthreads();
    for (int off = 1; off < 512; off <<= 1) {
        int add = (t >= off) ? sh[t - off] : 0;
        __syncthreads();
        sh[t] += add;
        __syncthreads();
    }
    if (t < nb) bsum[t] = sh[t] - v;
}

__global__ __launch_bounds__(256) void k_scan3(const int* __restrict__ cnt,
                                               const int* __restrict__ bsum,
                                               int* __restrict__ rowptr,
                                               int* __restrict__ cur) {
    __shared__ int sh[256];
    int base = blockIdx.x * 2048 + threadIdx.x * 8;
    int c[8]; int s = 0;
#pragma unroll
    for (int i = 0; i < 8; ++i) { int idx = base + i; c[i] = (idx < NROWS) ? cnt[idx] : 0; s += c[i]; }
    sh[threadIdx.x] = s;
    __syncthreads();
    int v = s;
    for (int off = 1; off < 256; off <<= 1) {
        int add = (threadIdx.x >= off) ? sh[threadIdx.x - off] : 0;
        __syncthreads();
        sh[threadIdx.x] += add;
        __syncthreads();
    }
    int excl = sh[threadIdx.x] - v + bsum[blockIdx.x];
#pragma unroll
    for (int i = 0; i < 8; ++i) {
        int idx = base + i;
        if (idx < NROWS) {
            rowptr[idx] = excl; cur[idx] = excl; excl += c[i];
            if (idx == NROWS - 1) rowptr[NROWS] = excl;
        }
    }
}

// ======== XCD-partitioned fill: each partition sweeps all edges, writes only
//          records for its contiguous row range (L2-merged full-line writes) ====
__device__ __forceinline__ void fill_graph(const int* __restrict__ src,
                                           const int* __restrict__ dst,
                                           const float* __restrict__ ea,
                                           int nE, int base, int rlo, int rhi,
                                           int tid0, int stride,
                                           int* __restrict__ cur,
                                           int2* __restrict__ pe) {
    for (int e = tid0; e < nE; e += stride) {
        int4 d4 = *(const int4*)(dst + e);
        int4 s4 = *(const int4*)(src + e);
        float4 w4 = *(const float4*)(ea + e);
        int dd[4] = {d4.x + base, d4.y + base, d4.z + base, d4.w + base};
        int ss[4] = {s4.x, s4.y, s4.z, s4.w};
        float ww[4] = {w4.x, w4.y, w4.z, w4.w};
#pragma unroll
        for (int i = 0; i < 4; ++i) {
            if (dd[i] >= rlo && dd[i] < rhi) {
                int slot = atomicAdd(&cur[dd[i]], 1);
                int2 r; r.x = ss[i]; r.y = __float_as_int(ww[i]);
                pe[slot] = r;
            }
        }
    }
}

__global__ __launch_bounds__(256) void k_fillpart(const int* __restrict__ src_cf,
                                                  const int* __restrict__ dst_cf,
                                                  const float* __restrict__ ea_cf,
                                                  const int* __restrict__ src_fp,
                                                  const int* __restrict__ dst_fp,
                                                  const float* __restrict__ ea_fp,
                                                  const int* __restrict__ src_pp,
                                                  const int* __restrict__ dst_pp,
                                                  const float* __restrict__ ea_pp,
                                                  int* __restrict__ cur,
                                                  int2* __restrict__ pe) {
    const int p = blockIdx.x & 7;                 // partition -> (empirically) XCD p
    const int blk = blockIdx.x >> 3;              // 0..FILL_BLOCKS/8-1
    const int rlo = part_bounds[p], rhi = part_bounds[p + 1];
    const int tid0 = (blk * 256 + (int)threadIdx.x) * 4;
    const int stride = (FILL_BLOCKS / 8) * 256 * 4;
    fill_graph(src_cf, dst_cf, ea_cf, E_CF, 0,       rlo, rhi, tid0, stride, cur, pe);
    fill_graph(src_fp, dst_fp, ea_fp, E_FP, FP_BASE, rlo, rhi, tid0, stride, cur, pe);
    fill_graph(src_pp, dst_pp, ea_pp, E_PP, PP_BASE, rlo, rhi, tid0, stride, cur, pe);
}

// ======== fused gather(cells->faces) + transform + concat ========
__global__ __launch_bounds__(256) void k_gather8_tf(const float* __restrict__ xc,
                                                    const int* __restrict__ ptr,
                                                    const int2* __restrict__ pe,
                                                    const float* __restrict__ x_face,
                                                    const float* __restrict__ W,
                                                    const float* __restrict__ b,
                                                    unsigned short* __restrict__ yfp) {
    __shared__ float Ws[512];
    __shared__ float bs[64];
    for (int i = threadIdx.x; i < 512; i += 256) Ws[i] = W[i];
    if (threadIdx.x < 64) bs[threadIdx.x] = b[threadIdx.x];
    __syncthreads();
    int r = blockIdx.x * 256 + threadIdx.x;
    if (r >= N_FACES) return;
    int e = ptr[r], end = ptr[r + 1];
    float a[8] = {};
    for (; e + 1 < end; e += 2) {
        int2 q0 = pe[e], q1 = pe[e + 1];
        float w0 = __int_as_float(q0.y), w1 = __int_as_float(q1.y);
        const float* p0 = xc + (size_t)q0.x * 8;
        const float* p1 = xc + (size_t)q1.x * 8;
        float4 u0 = *(const float4*)p0, u1 = *(const float4*)(p0 + 4);
        float4 v0 = *(const float4*)p1, v1 = *(const float4*)(p1 + 4);
        a[0] += w0 * u0.x + w1 * v0.x; a[1] += w0 * u0.y + w1 * v0.y;
        a[2] += w0 * u0.z + w1 * v0.z; a[3] += w0 * u0.w + w1 * v0.w;
        a[4] += w0 * u1.x + w1 * v1.x; a[5] += w0 * u1.y + w1 * v1.y;
        a[6] += w0 * u1.z + w1 * v1.z; a[7] += w0 * u1.w + w1 * v1.w;
    }
    if (e < end) {
        int2 q0 = pe[e];
        float w0 = __int_as_float(q0.y);
        const float* p0 = xc + (size_t)q0.x * 8;
        float4 u0 = *(const float4*)p0, u1 = *(const float4*)(p0 + 4);
        a[0] += w0 * u0.x; a[1] += w0 * u0.y; a[2] += w0 * u0.z; a[3] += w0 * u0.w;
        a[4] += w0 * u1.x; a[5] += w0 * u1.y; a[6] += w0 * u1.z; a[7] += w0 * u1.w;
    }
    unsigned short* orow = yfp + (size_t)r * 96;
#pragma unroll
    for (int c4 = 0; c4 < 4; ++c4) {
        int j0 = c4 * 16;
        float acc[16];
#pragma unroll
        for (int i = 0; i < 16; ++i) acc[i] = bs[j0 + i];
#pragma unroll
        for (int k = 0; k < 8; ++k) {
            float x = a[k];
            const float* wr = Ws + k * 64 + j0;
#pragma unroll
            for (int i = 0; i < 16; ++i) acc[i] += x * wr[i];
        }
        u16x8 o0, o1;
#pragma unroll
        for (int i = 0; i < 8; ++i) { o0[i] = f2bf(acc[i]); o1[i] = f2bf(acc[8 + i]); }
        *(u16x8*)(orow + j0) = o0;
        *(u16x8*)(orow + j0 + 8) = o1;
    }
    float4 xf0 = *(const float4*)(x_face + (size_t)r * 8);
    float4 xf1 = *(const float4*)(x_face + (size_t)r * 8 + 4);
    u16x8 xo;
    xo[0] = f2bf(xf0.x); xo[1] = f2bf(xf0.y); xo[2] = f2bf(xf0.z); xo[3] = f2bf(xf0.w);
    xo[4] = f2bf(xf1.x); xo[5] = f2bf(xf1.y); xo[6] = f2bf(xf1.z); xo[7] = f2bf(xf1.w);
    *(u16x8*)(orow + 64) = xo;
}

// ======== faces->points gather (96 bf16 cols): 2 rows/wave ========
__global__ __launch_bounds__(256) void k_gather96(const unsigned short* __restrict__ feat,
                                                  const int* __restrict__ ptr,
                                                  const int2* __restrict__ pe,
                                                  unsigned short* __restrict__ aggf, int nRows) {
    int gw = (blockIdx.x * 256 + threadIdx.x) >> 6;
    int lane = threadIdx.x & 63;
    int row = gw * 2 + (lane >> 5);
    int l = lane & 31;
    if (row >= nRows) return;
    int e = ptr[row], end = ptr[row + 1];
    float a0 = 0.f, a1 = 0.f, a2 = 0.f;
    for (; e + 1 < end; e += 2) {
        int2 q0 = pe[e], q1 = pe[e + 1];
        float w0 = __int_as_float(q0.y), w1 = __int_as_float(q1.y);
        const unsigned short* f0 = feat + (size_t)q0.x * 96 + l;
        const unsigned short* f1 = feat + (size_t)q1.x * 96 + l;
        unsigned short x0 = f0[0], x1 = f0[32], x2 = f0[64];
        unsigned short y0 = f1[0], y1 = f1[32], y2 = f1[64];
        a0 += w0 * bf2f(x0) + w1 * bf2f(y0);
        a1 += w0 * bf2f(x1) + w1 * bf2f(y1);
        a2 += w0 * bf2f(x2) + w1 * bf2f(y2);
    }
    if (e < end) {
        int2 q0 = pe[e];
        float w0 = __int_as_float(q0.y);
        const unsigned short* f0 = feat + (size_t)q0.x * 96 + l;
        a0 += w0 * bf2f(f0[0]); a1 += w0 * bf2f(f0[32]); a2 += w0 * bf2f(f0[64]);
    }
    unsigned short* o = aggf + (size_t)row * 96 + l;
    o[0] = f2bf(a0); o[32] = f2bf(a1); o[64] = f2bf(a2);
}

// ======== points->points gather (128 bf16 cols): 2 rows/wave ========
__global__ __launch_bounds__(256) void k_gather128pp(const unsigned short* __restrict__ feat,
                                                     const int* __restrict__ ptr,
                                                     const int2* __restrict__ pe,
                                                     unsigned short* __restrict__ aggp, int nRows) {
    int gw = (blockIdx.x * 256 + threadIdx.x) >> 6;
    int lane = threadIdx.x & 63;
    int row = gw * 2 + (lane >> 5);
    int l = lane & 31;
    if (row >= nRows) return;
    int e = ptr[row], end = ptr[row + 1];
    float a0 = 0.f, a1 = 0.f, a2 = 0.f, a3 = 0.f;
    for (; e + 1 < end; e += 2) {
        int2 q0 = pe[e], q1 = pe[e + 1];
        float w0 = __int_as_float(q0.y), w1 = __int_as_float(q1.y);
        const unsigned short* f0 = feat + ((size_t)q0.x << 7) + l;
        const unsigned short* f1 = feat + ((size_t)q1.x << 7) + l;
        unsigned short x0 = f0[0], x1 = f0[32], x2 = f0[64], x3 = f0[96];
        unsigned short y0 = f1[0], y1 = f1[32], y2 = f1[64], y3 = f1[96];
        a0 += w0 * bf2f(x0) + w1 * bf2f(y0);
        a1 += w0 * bf2f(x1) + w1 * bf2f(y1);
        a2 += w0 * bf2f(x2) + w1 * bf2f(y2);
        a3 += w0 * bf2f(x3) + w1 * bf2f(y3);
    }
    if (e < end) {
        int2 q0 = pe[e];
        float w0 = __int_as_float(q0.y);
        const unsigned short* f0 = feat + ((size_t)q0.x << 7) + l;
        a0 += w0 * bf2f(f0[0]);  a1 += w0 * bf2f(f0[32]);
        a2 += w0 * bf2f(f0[64]); a3 += w0 * bf2f(f0[96]);
    }
    unsigned short* o = aggp + ((size_t)row << 7) + l;
    o[0] = f2bf(a0); o[32] = f2bf(a1); o[64] = f2bf(a2); o[96] = f2bf(a3);
}

// ======== MFMA: y_ptb = bf16(aggf[200k,96] @ W_fp + b_fp) ========
__global__ __launch_bounds__(256) void k_mfma96(const unsigned short* __restrict__ A,
                                                const unsigned short* __restrict__ Bp,
                                                const float* __restrict__ bias,
                                                unsigned short* __restrict__ O) {
    const int w = threadIdx.x >> 6;
    const int lane = threadIdx.x & 63;
    const int rg = w >> 1, cg = w & 1;
    const int row0 = blockIdx.x * 32 + rg * 16;
    bf16x8 bfr[3][4];
#pragma unroll
    for (int ks = 0; ks < 3; ++ks)
#pragma unroll
        for (int c = 0; c < 4; ++c) {
            int ct = cg * 4 + c;
            bfr[ks][c] = *(const bf16x8*)(Bp + ((size_t)(ks * 8 + ct) * 64 + lane) * 8);
        }
    f32x4 acc[4] = {};
    const unsigned short* arow = A + (size_t)(row0 + (lane & 15)) * 96 + ((lane >> 4) * 8);
#pragma unroll
    for (int ks = 0; ks < 3; ++ks) {
        bf16x8 af = *(const bf16x8*)(arow + ks * 32);
#pragma unroll
        for (int c = 0; c < 4; ++c)
            acc[c] = __builtin_amdgcn_mfma_f32_16x16x32_bf16(af, bfr[ks][c], acc[c], 0, 0, 0);
    }
    const int rbase = row0 + (lane >> 4) * 4;
#pragma unroll
    for (int c = 0; c < 4; ++c) {
        int gcol = cg * 64 + c * 16 + (lane & 15);
        float bv = bias[gcol];
#pragma unroll
        for (int r = 0; r < 4; ++r)
            O[(size_t)(rbase + r) * 128 + gcol] = f2bf(acc[c][r] + bv);
    }
}

// ======== MFMA: out = [y_ptb | aggp] @ [W_rt;W_pp] + b_pp ========
__global__ __launch_bounds__(256) void k_mfma_fin(const unsigned short* __restrict__ A1,
                                                  const unsigned short* __restrict__ A2,
                                                  const unsigned short* __restrict__ Bp,
                                                  const float* __restrict__ bias,
                                                  float* __restrict__ out) {
    const int w = threadIdx.x >> 6;
    const int lane = threadIdx.x & 63;
    const int rg = w >> 1, cg = w & 1;
    const int row0 = blockIdx.x * 32 + rg * 16;
    bf16x8 bfr[8][4];
#pragma unroll
    for (int ks = 0; ks < 8; ++ks)
#pragma unroll
        for (int c = 0; c < 4; ++c) {
            int ct = cg * 4 + c;
            bfr[ks][c] = *(const bf16x8*)(Bp + ((size_t)(ks * 8 + ct) * 64 + lane) * 8);
        }
    f32x4 acc[4] = {};
    const unsigned short* a1 = A1 + (size_t)(row0 + (lane & 15)) * 128 + ((lane >> 4) * 8);
    const unsigned short* a2 = A2 + (size_t)(row0 + (lane & 15)) * 128 + ((lane >> 4) * 8);
#pragma unroll
    for (int ks = 0; ks < 4; ++ks) {
        bf16x8 af = *(const bf16x8*)(a1 + ks * 32);
#pragma unroll
        for (int c = 0; c < 4; ++c)
            acc[c] = __builtin_amdgcn_mfma_f32_16x16x32_bf16(af, bfr[ks][c], acc[c], 0, 0, 0);
    }
#pragma unroll
    for (int ks = 0; ks < 4; ++ks) {
        bf16x8 af = *(const bf16x8*)(a2 + ks * 32);
#pragma unroll
        for (int c = 0; c < 4; ++c)
            acc[c] = __builtin_amdgcn_mfma_f32_16x16x32_bf16(af, bfr[ks + 4][c], acc[c], 0, 0, 0);
    }
    const int rbase = row0 + (lane >> 4) * 4;
#pragma unroll
    for (int c = 0; c < 4; ++c) {
        int gcol = cg * 64 + c * 16 + (lane & 15);
        float bv = bias[gcol];
#pragma unroll
        for (int r = 0; r < 4; ++r)
            out[(size_t)(rbase + r) * 128 + gcol] = acc[c][r] + bv;
    }
}

extern "C" void kernel_launch(void* const* d_in, const int* in_sizes, int n_in,
                              void* d_out, int out_size, void* d_ws, size_t ws_size,
                              hipStream_t stream) {
    const float* x_centers = (const float*)d_in[0];
    const float* x_face    = (const float*)d_in[1];
    const float* W_cf      = (const float*)d_in[2];
    const float* b_cf      = (const float*)d_in[3];
    const float* W_fp      = (const float*)d_in[4];
    const float* b_fp      = (const float*)d_in[5];
    const float* W_pp      = (const float*)d_in[6];
    const float* W_rt      = (const float*)d_in[7];
    const float* b_pp      = (const float*)d_in[8];
    const float* ea_cf     = (const float*)d_in[9];
    const float* ea_fp     = (const float*)d_in[10];
    const float* ea_pp     = (const float*)d_in[11];
    const int* src_cf      = (const int*)d_in[12];
    const int* dst_cf      = (const int*)d_in[13];
    const int* src_fp      = (const int*)d_in[14];
    const int* dst_fp      = (const int*)d_in[15];
    const int* src_pp      = (const int*)d_in[16];
    const int* dst_pp      = (const int*)d_in[17];
    float* out = (float*)d_out;

    char* ws = (char*)d_ws;
    unsigned short* yfp    = (unsigned short*)(ws + 0);           // bf16 [400k][96]  76.8MB
    unsigned short* aggf   = (unsigned short*)(ws + 80000000);    // bf16 [200k][96]  38.4MB
    unsigned short* y_ptb  = (unsigned short*)(ws + 120000000);   // bf16 [200k][128] 51.2MB
    unsigned short* aggp   = (unsigned short*)(ws + 172000000);   // bf16 [200k][128] 51.2MB
    int2* pe_all           = (int2*)(ws + 224000000);             // 2.8M recs 22.4MB
    int*  cnt_all          = (int*)(ws + 247000000);              // 800000 (counts -> cursors)
    int*  ptr_all          = (int*)(ws + 251000000);              // 800001 rowptr
    int*  bsum             = (int*)(ws + 255000000);              // 391
    unsigned short* Bp_fp  = (unsigned short*)(ws + 255100000);   // 24KB
    unsigned short* Bp_fin = (unsigned short*)(ws + 255200000);   // 64KB

    // CSR build
    k_pre<<<3301, 256, 0, stream>>>(cnt_all, W_fp, W_rt, W_pp, Bp_fp, Bp_fin);
    k_hist3<<<10938, 256, 0, stream>>>(dst_cf, dst_fp, dst_pp, cnt_all);
    k_scan1<<<391, 256, 0, stream>>>(cnt_all, bsum);
    k_scan2<<<1, 512, 0, stream>>>(bsum, 391);
    k_scan3<<<391, 256, 0, stream>>>(cnt_all, bsum, ptr_all, cnt_all);
    // XCD-partitioned fill (all three graphs, L2-merged record writes)
    k_fillpart<<<FILL_BLOCKS, 256, 0, stream>>>(src_cf, dst_cf, ea_cf,
                                                src_fp, dst_fp, ea_fp,
                                                src_pp, dst_pp, ea_pp,
                                                cnt_all, pe_all);
    // pipeline
    k_gather8_tf<<<1563, 256, 0, stream>>>(x_centers, ptr_all, pe_all, x_face, W_cf, b_cf, yfp);
    k_gather96<<<25000, 256, 0, stream>>>(yfp, ptr_all + FP_BASE, pe_all, aggf, N_POINTS);
    k_mfma96<<<6250, 256, 0, stream>>>(aggf, Bp_fp, b_fp, y_ptb);
    k_gather128pp<<<25000, 256, 0, stream>>>(y_ptb, ptr_all + PP_BASE, pe_all, aggp, N_POINTS);
    k_mfma_fin<<<6250, 256, 0, stream>>>(y_ptb, aggp, Bp_fin, b_pp, out);
}